// Round 1
// baseline (2318.798 us; speedup 1.0000x reference)
//
#include <hip/hip_runtime.h>

#define N_NODES 100000
#define D_IN 128
#define HID 256
#define D_OUT 64

// ---------------- degree / normalization ----------------

__global__ void k_deg_init(float* deg, int n) {
    int i = blockIdx.x * blockDim.x + threadIdx.x;
    if (i < n) deg[i] = 1.0f;  // self-loop contributes 1
}

__global__ void k_deg_accum(const int* dst, int E, float* deg) {
    int e = blockIdx.x * blockDim.x + threadIdx.x;
    if (e < E) atomicAdd(&deg[dst[e]], 1.0f);
}

__global__ void k_dinv(float* deg, int n) {
    int i = blockIdx.x * blockDim.x + threadIdx.x;
    if (i < n) deg[i] = rsqrtf(deg[i]);  // deg >= 1 always (self-loop)
}

// ---------------- layer-1 aggregation: agg = A_norm @ x (128 dims) ----------------

// self-loop term: agg[i] = dinv[i]^2 * x[i]
__global__ void k_agg1_init(const float* __restrict__ x, const float* __restrict__ dinv,
                            float* __restrict__ agg) {
    int i = blockIdx.x * blockDim.x + threadIdx.x;  // float4 index
    if (i >= N_NODES * (D_IN / 4)) return;
    int node = i / (D_IN / 4);
    float s = dinv[node];
    s = s * s;
    float4 v = ((const float4*)x)[i];
    v.x *= s; v.y *= s; v.z *= s; v.w *= s;
    ((float4*)agg)[i] = v;
}

// edge term: agg[dst] += dinv[src]*dinv[dst] * x[src]; 32 lanes per edge (float4 each)
__global__ void k_agg1_edges(const int* __restrict__ src, const int* __restrict__ dst, int E,
                             const float* __restrict__ x, const float* __restrict__ dinv,
                             float* __restrict__ agg) {
    int t = blockIdx.x * blockDim.x + threadIdx.x;
    int e = t >> 5;
    int lane = t & 31;
    if (e >= E) return;
    int s = src[e], d = dst[e];
    float w = dinv[s] * dinv[d];
    float4 v = ((const float4*)(x + (size_t)s * D_IN))[lane];
    float* ap = agg + (size_t)d * D_IN + lane * 4;
    atomicAdd(ap + 0, w * v.x);
    atomicAdd(ap + 1, w * v.y);
    atomicAdd(ap + 2, w * v.z);
    atomicAdd(ap + 3, w * v.w);
}

// ---------------- fused GEMM chain: m = relu(agg@W1 + b1) @ W2 ----------------

#define TR 16  // rows per block

__global__ __launch_bounds__(256) void k_fused_gemm(const float* __restrict__ agg,
                                                    const float* __restrict__ W1,
                                                    const float* __restrict__ b1,
                                                    const float* __restrict__ W2,
                                                    float* __restrict__ m) {
    __shared__ float sA[TR * D_IN];   // 8 KB
    __shared__ float sH[TR * HID];    // 16 KB
    int t = threadIdx.x;
    size_t row0 = (size_t)blockIdx.x * TR;

    // stage 16 agg rows
    const float4* gsrc = (const float4*)(agg + row0 * D_IN);
    float4* ls = (float4*)sA;
    for (int i = t; i < TR * D_IN / 4; i += 256) ls[i] = gsrc[i];
    __syncthreads();

    // GEMM1: each thread owns column j = t of W1, computes 16 rows
    float acc[TR];
#pragma unroll
    for (int r = 0; r < TR; r++) acc[r] = 0.0f;
    for (int k0 = 0; k0 < D_IN; k0 += 4) {
        float w0 = W1[(k0 + 0) * HID + t];
        float w1 = W1[(k0 + 1) * HID + t];
        float w2 = W1[(k0 + 2) * HID + t];
        float w3 = W1[(k0 + 3) * HID + t];
#pragma unroll
        for (int r = 0; r < TR; r++) {
            float4 a = *(const float4*)(sA + r * D_IN + k0);
            acc[r] += a.x * w0 + a.y * w1 + a.z * w2 + a.w * w3;
        }
    }
    float bb = b1[t];
#pragma unroll
    for (int r = 0; r < TR; r++) {
        float h = acc[r] + bb;
        sH[r * HID + t] = h > 0.0f ? h : 0.0f;
    }
    __syncthreads();

    // GEMM2: j = t&63, row group rg = t>>6 covering rows rg*4 .. rg*4+3
    int j = t & 63, rg = t >> 6;
    float a0 = 0, a1 = 0, a2 = 0, a3 = 0;
    for (int k0 = 0; k0 < HID; k0 += 4) {
        float w0 = W2[(k0 + 0) * D_OUT + j];
        float w1 = W2[(k0 + 1) * D_OUT + j];
        float w2 = W2[(k0 + 2) * D_OUT + j];
        float w3 = W2[(k0 + 3) * D_OUT + j];
        float4 h0 = *(const float4*)(sH + (rg * 4 + 0) * HID + k0);
        float4 h1 = *(const float4*)(sH + (rg * 4 + 1) * HID + k0);
        float4 h2 = *(const float4*)(sH + (rg * 4 + 2) * HID + k0);
        float4 h3 = *(const float4*)(sH + (rg * 4 + 3) * HID + k0);
        a0 += h0.x * w0 + h0.y * w1 + h0.z * w2 + h0.w * w3;
        a1 += h1.x * w0 + h1.y * w1 + h1.z * w2 + h1.w * w3;
        a2 += h2.x * w0 + h2.y * w1 + h2.z * w2 + h2.w * w3;
        a3 += h3.x * w0 + h3.y * w1 + h3.z * w2 + h3.w * w3;
    }
    float* mp = m + row0 * D_OUT;
    mp[(rg * 4 + 0) * D_OUT + j] = a0;
    mp[(rg * 4 + 1) * D_OUT + j] = a1;
    mp[(rg * 4 + 2) * D_OUT + j] = a2;
    mp[(rg * 4 + 3) * D_OUT + j] = a3;
}

// ---------------- layer-2 aggregation: out = A_norm @ m + b2 (64 dims) ----------------

__global__ void k_out_init(const float* __restrict__ m, const float* __restrict__ dinv,
                           const float* __restrict__ b2, float* __restrict__ out) {
    int i = blockIdx.x * blockDim.x + threadIdx.x;  // float4 index
    if (i >= N_NODES * (D_OUT / 4)) return;
    int node = i / (D_OUT / 4);
    float s = dinv[node];
    s = s * s;
    float4 v = ((const float4*)m)[i];
    float4 bv = ((const float4*)b2)[i % (D_OUT / 4)];
    v.x = v.x * s + bv.x;
    v.y = v.y * s + bv.y;
    v.z = v.z * s + bv.z;
    v.w = v.w * s + bv.w;
    ((float4*)out)[i] = v;
}

__global__ void k_out_edges(const int* __restrict__ src, const int* __restrict__ dst, int E,
                            const float* __restrict__ m, const float* __restrict__ dinv,
                            float* __restrict__ out) {
    int t = blockIdx.x * blockDim.x + threadIdx.x;
    int e = t >> 4;
    int lane = t & 15;
    if (e >= E) return;
    int s = src[e], d = dst[e];
    float w = dinv[s] * dinv[d];
    float4 v = ((const float4*)(m + (size_t)s * D_OUT))[lane];
    float* op = out + (size_t)d * D_OUT + lane * 4;
    atomicAdd(op + 0, w * v.x);
    atomicAdd(op + 1, w * v.y);
    atomicAdd(op + 2, w * v.z);
    atomicAdd(op + 3, w * v.w);
}

// ---------------- launch ----------------

extern "C" void kernel_launch(void* const* d_in, const int* in_sizes, int n_in,
                              void* d_out, int out_size, void* d_ws, size_t ws_size,
                              hipStream_t stream) {
    const float* x  = (const float*)d_in[0];
    const int*   ei = (const int*)d_in[1];
    const float* W1 = (const float*)d_in[2];
    const float* b1 = (const float*)d_in[3];
    const float* W2 = (const float*)d_in[4];
    const float* b2 = (const float*)d_in[5];
    float* out = (float*)d_out;

    const int E = in_sizes[1] / 2;
    const int* src = ei;
    const int* dst = ei + E;

    // workspace layout (floats)
    float* ws = (float*)d_ws;
    float* dinv = ws;                          // N
    float* agg  = ws + 100352;                 // N*128  (aligned start)
    float* m    = agg + (size_t)N_NODES * D_IN;  // N*64

    // degree + dinv
    k_deg_init<<<(N_NODES + 255) / 256, 256, 0, stream>>>(dinv, N_NODES);
    k_deg_accum<<<(E + 255) / 256, 256, 0, stream>>>(dst, E, dinv);
    k_dinv<<<(N_NODES + 255) / 256, 256, 0, stream>>>(dinv, N_NODES);

    // layer-1 aggregation on x (128 dims)
    k_agg1_init<<<(N_NODES * (D_IN / 4) + 255) / 256, 256, 0, stream>>>(x, dinv, agg);
    k_agg1_edges<<<((size_t)E * 32 + 255) / 256, 256, 0, stream>>>(src, dst, E, x, dinv, agg);

    // fused GEMM chain -> m
    k_fused_gemm<<<N_NODES / TR, 256, 0, stream>>>(agg, W1, b1, W2, m);

    // layer-2 aggregation on m (64 dims) + bias
    k_out_init<<<(N_NODES * (D_OUT / 4) + 255) / 256, 256, 0, stream>>>(m, dinv, b2, out);
    k_out_edges<<<((size_t)E * 16 + 255) / 256, 256, 0, stream>>>(src, dst, E, m, dinv, out);
}

// Round 2
// 682.600 us; speedup vs baseline: 3.3970x; 3.3970x over previous
//
#include <hip/hip_runtime.h>

#define N_NODES 100000
#define D_IN 128
#define HID 256
#define D_OUT 64

// ---------------- CSR build ----------------

__global__ void k_zero(int* p, int n) {
    int i = blockIdx.x * blockDim.x + threadIdx.x;
    if (i < n) p[i] = 0;
}

__global__ void k_count(const int* __restrict__ dst, int E, int* __restrict__ cnt) {
    int e = blockIdx.x * blockDim.x + threadIdx.x;
    if (e < E) atomicAdd(&cnt[dst[e]], 1);
}

__global__ void k_dinv(const int* __restrict__ cnt, float* __restrict__ dinv, int n) {
    int i = blockIdx.x * blockDim.x + threadIdx.x;
    if (i < n) dinv[i] = rsqrtf((float)cnt[i] + 1.0f);  // +1 self-loop
}

#define SCAN_T 1024
__global__ __launch_bounds__(SCAN_T) void k_scan(const int* __restrict__ cnt,
                                                 int* __restrict__ row_ptr,
                                                 int* __restrict__ cursor, int n) {
    __shared__ int s[SCAN_T];
    int t = threadIdx.x;
    int chunk = (n + SCAN_T - 1) / SCAN_T;
    int lo = t * chunk, hi = lo + chunk;
    if (hi > n) hi = n;
    int sum = 0;
    for (int i = lo; i < hi; i++) sum += cnt[i];
    s[t] = sum;
    __syncthreads();
    for (int off = 1; off < SCAN_T; off <<= 1) {
        int v = (t >= off) ? s[t - off] : 0;
        __syncthreads();
        s[t] += v;
        __syncthreads();
    }
    int run = (t == 0) ? 0 : s[t - 1];
    for (int i = lo; i < hi; i++) {
        int c = cnt[i];
        row_ptr[i] = run;
        cursor[i] = run;
        run += c;
    }
    if (t == SCAN_T - 1) row_ptr[n] = run;
}

__global__ void k_fill(const int* __restrict__ src, const int* __restrict__ dst, int E,
                       const float* __restrict__ dinv, int* __restrict__ cursor,
                       int* __restrict__ col, float* __restrict__ wgt) {
    int e = blockIdx.x * blockDim.x + threadIdx.x;
    if (e >= E) return;
    int s = src[e], d = dst[e];
    int pos = atomicAdd(&cursor[d], 1);
    col[pos] = s;
    wgt[pos] = dinv[s] * dinv[d];
}

// ---------------- layer-1 pull aggregation: agg = A_norm @ x (128 dims) ----------------
// one 64-lane wave per node, float2 per lane

__global__ __launch_bounds__(256) void k_pull1(const int* __restrict__ row_ptr,
                                               const int* __restrict__ col,
                                               const float* __restrict__ wgt,
                                               const float* __restrict__ x,
                                               const float* __restrict__ dinv,
                                               float* __restrict__ agg) {
    int wid = (blockIdx.x * blockDim.x + threadIdx.x) >> 6;
    int lane = threadIdx.x & 63;
    if (wid >= N_NODES) return;
    int beg = row_ptr[wid], end = row_ptr[wid + 1];
    float di = dinv[wid];
    float2 v = ((const float2*)(x + (size_t)wid * D_IN))[lane];
    float w0 = di * di;
    float ax = w0 * v.x, ay = w0 * v.y;
    for (int e = beg; e < end; e++) {
        int s = col[e];
        float w = wgt[e];
        float2 xv = ((const float2*)(x + (size_t)s * D_IN))[lane];
        ax += w * xv.x;
        ay += w * xv.y;
    }
    float2 r;
    r.x = ax;
    r.y = ay;
    ((float2*)(agg + (size_t)wid * D_IN))[lane] = r;
}

// ---------------- fused GEMM chain: m = relu(agg@W1 + b1) @ W2 ----------------
// m is written back into the agg buffer (row stride 128, first 64 cols)

#define TR 16  // rows per block

__global__ __launch_bounds__(256) void k_fused_gemm(float* __restrict__ agg,
                                                    const float* __restrict__ W1,
                                                    const float* __restrict__ b1,
                                                    const float* __restrict__ W2) {
    __shared__ float sA[TR * D_IN];   // 8 KB
    __shared__ float sH[TR * HID];    // 16 KB
    int t = threadIdx.x;
    size_t row0 = (size_t)blockIdx.x * TR;

    const float4* gsrc = (const float4*)(agg + row0 * D_IN);
    float4* ls = (float4*)sA;
    for (int i = t; i < TR * D_IN / 4; i += 256) ls[i] = gsrc[i];
    __syncthreads();

    // GEMM1: thread t owns column t of W1
    float acc[TR];
#pragma unroll
    for (int r = 0; r < TR; r++) acc[r] = 0.0f;
    for (int k0 = 0; k0 < D_IN; k0 += 4) {
        float w0 = W1[(k0 + 0) * HID + t];
        float w1 = W1[(k0 + 1) * HID + t];
        float w2 = W1[(k0 + 2) * HID + t];
        float w3 = W1[(k0 + 3) * HID + t];
#pragma unroll
        for (int r = 0; r < TR; r++) {
            float4 a = *(const float4*)(sA + r * D_IN + k0);
            acc[r] += a.x * w0 + a.y * w1 + a.z * w2 + a.w * w3;
        }
    }
    float bb = b1[t];
#pragma unroll
    for (int r = 0; r < TR; r++) {
        float h = acc[r] + bb;
        sH[r * HID + t] = h > 0.0f ? h : 0.0f;
    }
    __syncthreads();

    // GEMM2: j = t&63, row group rg = t>>6 covers rows rg*4..rg*4+3
    int j = t & 63, rg = t >> 6;
    float a0 = 0, a1 = 0, a2 = 0, a3 = 0;
    for (int k0 = 0; k0 < HID; k0 += 4) {
        float w0 = W2[(k0 + 0) * D_OUT + j];
        float w1 = W2[(k0 + 1) * D_OUT + j];
        float w2 = W2[(k0 + 2) * D_OUT + j];
        float w3 = W2[(k0 + 3) * D_OUT + j];
        float4 h0 = *(const float4*)(sH + (rg * 4 + 0) * HID + k0);
        float4 h1 = *(const float4*)(sH + (rg * 4 + 1) * HID + k0);
        float4 h2 = *(const float4*)(sH + (rg * 4 + 2) * HID + k0);
        float4 h3 = *(const float4*)(sH + (rg * 4 + 3) * HID + k0);
        a0 += h0.x * w0 + h0.y * w1 + h0.z * w2 + h0.w * w3;
        a1 += h1.x * w0 + h1.y * w1 + h1.z * w2 + h1.w * w3;
        a2 += h2.x * w0 + h2.y * w1 + h2.z * w2 + h2.w * w3;
        a3 += h3.x * w0 + h3.y * w1 + h3.z * w2 + h3.w * w3;
    }
    __syncthreads();  // ensure all staging reads done before overwriting rows
    float* mp = agg + row0 * D_IN;
    mp[(rg * 4 + 0) * D_IN + j] = a0;
    mp[(rg * 4 + 1) * D_IN + j] = a1;
    mp[(rg * 4 + 2) * D_IN + j] = a2;
    mp[(rg * 4 + 3) * D_IN + j] = a3;
}

// ---------------- layer-2 pull aggregation: out = A_norm @ m + b2 (64 dims) ----------------
// one 64-lane wave per node, 1 float per lane; m rows live at agg stride 128

__global__ __launch_bounds__(256) void k_pull2(const int* __restrict__ row_ptr,
                                               const int* __restrict__ col,
                                               const float* __restrict__ wgt,
                                               const float* __restrict__ m,
                                               const float* __restrict__ dinv,
                                               const float* __restrict__ b2,
                                               float* __restrict__ out) {
    int wid = (blockIdx.x * blockDim.x + threadIdx.x) >> 6;
    int lane = threadIdx.x & 63;
    if (wid >= N_NODES) return;
    int beg = row_ptr[wid], end = row_ptr[wid + 1];
    float di = dinv[wid];
    float acc = di * di * m[(size_t)wid * D_IN + lane] + b2[lane];
    for (int e = beg; e < end; e++) {
        acc += wgt[e] * m[(size_t)col[e] * D_IN + lane];
    }
    out[(size_t)wid * D_OUT + lane] = acc;
}

// ---------------- launch ----------------

extern "C" void kernel_launch(void* const* d_in, const int* in_sizes, int n_in,
                              void* d_out, int out_size, void* d_ws, size_t ws_size,
                              hipStream_t stream) {
    const float* x  = (const float*)d_in[0];
    const int*   ei = (const int*)d_in[1];
    const float* W1 = (const float*)d_in[2];
    const float* b1 = (const float*)d_in[3];
    const float* W2 = (const float*)d_in[4];
    const float* b2 = (const float*)d_in[5];
    float* out = (float*)d_out;

    const int E = in_sizes[1] / 2;
    const int* src = ei;
    const int* dst = ei + E;

    // workspace layout (all 256B-aligned offsets)
    int* cnt     = (int*)d_ws;              // N
    int* row_ptr = cnt + 100096;            // N+1
    int* cursor  = row_ptr + 100096;        // N
    int* col     = cursor + 100096;         // E
    float* dinv  = (float*)(col + 800000);  // N
    float* wgt   = dinv + 100096;           // E
    float* agg   = wgt + 800000;            // N*128 (m aliased, stride 128)

    // CSR build + normalization
    k_zero<<<(N_NODES + 255) / 256, 256, 0, stream>>>(cnt, N_NODES);
    k_count<<<(E + 255) / 256, 256, 0, stream>>>(dst, E, cnt);
    k_dinv<<<(N_NODES + 255) / 256, 256, 0, stream>>>(cnt, dinv, N_NODES);
    k_scan<<<1, SCAN_T, 0, stream>>>(cnt, row_ptr, cursor, N_NODES);
    k_fill<<<(E + 255) / 256, 256, 0, stream>>>(src, dst, E, dinv, cursor, col, wgt);

    // layer-1 pull aggregation (128 dims)
    k_pull1<<<(N_NODES * 64 + 255) / 256, 256, 0, stream>>>(row_ptr, col, wgt, x, dinv, agg);

    // fused GEMM chain, m written into agg (stride 128)
    k_fused_gemm<<<N_NODES / TR, 256, 0, stream>>>(agg, W1, b1, W2);

    // layer-2 pull aggregation (64 dims) + bias
    k_pull2<<<(N_NODES * 64 + 255) / 256, 256, 0, stream>>>(row_ptr, col, wgt, agg, dinv, b2, out);
}

// Round 4
// 242.875 us; speedup vs baseline: 9.5473x; 2.8105x over previous
//
#include <hip/hip_runtime.h>
#include <hip/hip_bf16.h>

#define N_NODES 100000
#define D_IN 128
#define HID 256
#define D_OUT 64
#define TR 32

typedef __attribute__((ext_vector_type(8))) short bf8;
typedef __attribute__((ext_vector_type(4))) float f4;

static __device__ __forceinline__ unsigned short f2bf(float f) {
    __hip_bfloat16 h = __float2bfloat16(f);
    return *reinterpret_cast<unsigned short*>(&h);
}
static __device__ __forceinline__ float bflo(unsigned int u) { return __uint_as_float(u << 16); }
static __device__ __forceinline__ float bfhi(unsigned int u) { return __uint_as_float(u & 0xffff0000u); }

// ---------------- CSR build ----------------

__global__ void k_zero(int* p, int n) {
    int i = blockIdx.x * blockDim.x + threadIdx.x;
    if (i < n) p[i] = 0;
}

__global__ void k_count(const int* __restrict__ dst, int E, int* __restrict__ cnt) {
    int e = blockIdx.x * blockDim.x + threadIdx.x;
    if (e < E) atomicAdd(&cnt[dst[e]], 1);
}

__global__ void k_dinv(const int* __restrict__ cnt, float* __restrict__ dinv, int n) {
    int i = blockIdx.x * blockDim.x + threadIdx.x;
    if (i < n) dinv[i] = rsqrtf((float)cnt[i] + 1.0f);  // +1 self-loop
}

// per-block exclusive prefix into row_ptr, block totals into bsum
__global__ __launch_bounds__(256) void k_scan_part(const int* __restrict__ cnt,
                                                   int* __restrict__ row_ptr,
                                                   int* __restrict__ bsum, int n) {
    __shared__ int s[256];
    int t = threadIdx.x, i = blockIdx.x * 256 + t;
    int v = (i < n) ? cnt[i] : 0;
    s[t] = v;
    __syncthreads();
    for (int off = 1; off < 256; off <<= 1) {
        int u = (t >= off) ? s[t - off] : 0;
        __syncthreads();
        s[t] += u;
        __syncthreads();
    }
    if (i < n) row_ptr[i] = s[t] - v;  // exclusive within block
    if (t == 255) bsum[blockIdx.x] = s[255];
}

// single block: exclusive-scan bsum in place; write row_ptr[n] = grand total
__global__ __launch_bounds__(512) void k_scan_base(int* __restrict__ bsum,
                                                   int* __restrict__ row_ptr, int nb, int n) {
    __shared__ int s[512];
    int t = threadIdx.x;
    int v = (t < nb) ? bsum[t] : 0;
    s[t] = v;
    __syncthreads();
    for (int off = 1; off < 512; off <<= 1) {
        int u = (t >= off) ? s[t - off] : 0;
        __syncthreads();
        s[t] += u;
        __syncthreads();
    }
    if (t < nb) bsum[t] = s[t] - v;  // exclusive base
    if (t == 511) row_ptr[n] = s[511];
}

// add block bases; final row_ptr and cursor (cursor aliases cnt — counts are dead)
__global__ void k_scan_fin(int* __restrict__ row_ptr, const int* __restrict__ bsum,
                           int* __restrict__ cursor, int n) {
    int i = blockIdx.x * blockDim.x + threadIdx.x;
    if (i >= n) return;
    int v = row_ptr[i] + bsum[i >> 8];
    row_ptr[i] = v;
    cursor[i] = v;
}

__global__ void k_fill(const int* __restrict__ src, const int* __restrict__ dst, int E,
                       const float* __restrict__ dinv, int* __restrict__ cursor,
                       int* __restrict__ col, float* __restrict__ wgt) {
    int e = blockIdx.x * blockDim.x + threadIdx.x;
    if (e >= E) return;
    int s = src[e], d = dst[e];
    int pos = atomicAdd(&cursor[d], 1);
    col[pos] = s;
    wgt[pos] = dinv[s] * dinv[d];
}

// ---------------- conversions ----------------

__global__ void k_cvt_x(const float* __restrict__ x, unsigned short* __restrict__ xb, int n4) {
    int i = blockIdx.x * blockDim.x + threadIdx.x;
    if (i >= n4) return;
    float4 v = ((const float4*)x)[i];
    unsigned long long o = (unsigned long long)f2bf(v.x) | ((unsigned long long)f2bf(v.y) << 16) |
                           ((unsigned long long)f2bf(v.z) << 32) |
                           ((unsigned long long)f2bf(v.w) << 48);
    ((unsigned long long*)xb)[i] = o;
}

// W1t[n][k] = bf16(W1[k][n]), 256x128
__global__ void k_cvt_w1(const float* __restrict__ W1, unsigned short* __restrict__ W1t) {
    int i = blockIdx.x * blockDim.x + threadIdx.x;
    if (i >= HID * D_IN) return;
    int n = i >> 7, k = i & 127;
    W1t[i] = f2bf(W1[k * HID + n]);
}

// W2t[n][k] = bf16(W2[k][n]), 64x256
__global__ void k_cvt_w2(const float* __restrict__ W2, unsigned short* __restrict__ W2t) {
    int i = blockIdx.x * blockDim.x + threadIdx.x;
    if (i >= D_OUT * HID) return;
    int n = i >> 8, k = i & 255;
    W2t[i] = f2bf(W2[k * D_OUT + n]);
}

// ---------------- layer-1 pull: agg = A_norm @ x, bf16 in / bf16 out ----------------
// one wave per node; lane holds cols {2*lane, 2*lane+1} packed bf16x2

__global__ __launch_bounds__(256) void k_pull1(const int* __restrict__ row_ptr,
                                               const int* __restrict__ col,
                                               const float* __restrict__ wgt,
                                               const unsigned int* __restrict__ xb,
                                               const float* __restrict__ dinv,
                                               unsigned int* __restrict__ agg) {
    int wid = (blockIdx.x * blockDim.x + threadIdx.x) >> 6;
    int lane = threadIdx.x & 63;
    if (wid >= N_NODES) return;
    int beg = row_ptr[wid], end = row_ptr[wid + 1];
    float di = dinv[wid];
    float w0 = di * di;
    unsigned int u = xb[(size_t)wid * 64 + lane];
    float ax = w0 * bflo(u), ay = w0 * bfhi(u);
    int e = beg;
    for (; e + 4 <= end; e += 4) {
        int s0 = col[e], s1 = col[e + 1], s2 = col[e + 2], s3 = col[e + 3];
        float w_0 = wgt[e], w_1 = wgt[e + 1], w_2 = wgt[e + 2], w_3 = wgt[e + 3];
        unsigned int u0 = xb[(size_t)s0 * 64 + lane];
        unsigned int u1 = xb[(size_t)s1 * 64 + lane];
        unsigned int u2 = xb[(size_t)s2 * 64 + lane];
        unsigned int u3 = xb[(size_t)s3 * 64 + lane];
        ax += w_0 * bflo(u0);
        ay += w_0 * bfhi(u0);
        ax += w_1 * bflo(u1);
        ay += w_1 * bfhi(u1);
        ax += w_2 * bflo(u2);
        ay += w_2 * bfhi(u2);
        ax += w_3 * bflo(u3);
        ay += w_3 * bfhi(u3);
    }
    for (; e < end; e++) {
        int s = col[e];
        float w = wgt[e];
        unsigned int uu = xb[(size_t)s * 64 + lane];
        ax += w * bflo(uu);
        ay += w * bfhi(uu);
    }
    unsigned int o = (unsigned int)f2bf(ax) | ((unsigned int)f2bf(ay) << 16);
    agg[(size_t)wid * 64 + lane] = o;
}

// ---------------- fused GEMM chain (MFMA): m = relu(agg@W1+b1)@W2 ----------------
// m (fp32, 64 cols = 256 B/row) is written IN PLACE over the agg rows this block
// consumed (each agg row is 128 bf16 = 256 B). Safe: rows staged to LDS before
// first barrier; no other block touches them.

__global__ __launch_bounds__(256) void k_fused_mfma(unsigned short* __restrict__ agg,
                                                    const unsigned short* __restrict__ W1t,
                                                    const float* __restrict__ b1,
                                                    const unsigned short* __restrict__ W2t) {
    __shared__ char sA[TR * D_IN * 2];  // 8 KB, row stride 256B
    __shared__ char sH[TR * HID * 2];   // 16 KB, row stride 512B
    int t = threadIdx.x, wave = t >> 6, lane = t & 63;
    int lr = lane & 15, lg = lane >> 4;
    size_t row0 = (size_t)blockIdx.x * TR;

    // stage A tile: 512 x 16B chunks, XOR swizzle byte ^= (row&7)<<4
    {
        const float4* g = (const float4*)(agg + row0 * D_IN);
#pragma unroll
        for (int c0 = 0; c0 < 2; c0++) {
            int c = c0 * 256 + t;
            int row = c >> 4;
            *(float4*)(sA + ((c * 16) ^ ((row & 7) << 4))) = g[c];
        }
    }
    __syncthreads();

    // GEMM1: wave covers cols wave*64 .. wave*64+63 (4 tiles), both 16-row halves
    f4 acc1[4][2];
#pragma unroll
    for (int tt = 0; tt < 4; tt++)
#pragma unroll
        for (int h = 0; h < 2; h++) acc1[tt][h] = (f4){0.f, 0.f, 0.f, 0.f};

#pragma unroll
    for (int kk = 0; kk < 4; kk++) {
        bf8 a0 = *(const bf8*)(sA + ((lr * 256 + kk * 64 + lg * 16) ^ ((lr & 7) << 4)));
        bf8 a1 = *(const bf8*)(sA + (((16 + lr) * 256 + kk * 64 + lg * 16) ^ (((16 + lr) & 7) << 4)));
#pragma unroll
        for (int tt = 0; tt < 4; tt++) {
            bf8 b = *(const bf8*)(W1t + (size_t)(wave * 64 + tt * 16 + lr) * D_IN + kk * 32 + lg * 8);
            acc1[tt][0] = __builtin_amdgcn_mfma_f32_16x16x32_bf16(a0, b, acc1[tt][0], 0, 0, 0);
            acc1[tt][1] = __builtin_amdgcn_mfma_f32_16x16x32_bf16(a1, b, acc1[tt][1], 0, 0, 0);
        }
    }

    // epilogue 1: bias + relu + cvt bf16 -> sH
#pragma unroll
    for (int tt = 0; tt < 4; tt++) {
        int colc = wave * 64 + tt * 16 + lr;
        float bias = b1[colc];
#pragma unroll
        for (int h = 0; h < 2; h++) {
#pragma unroll
            for (int ri = 0; ri < 4; ri++) {
                int row = h * 16 + lg * 4 + ri;
                float hv = acc1[tt][h][ri] + bias;
                hv = hv > 0.f ? hv : 0.f;
                *(unsigned short*)(sH + ((row * 512 + colc * 2) ^ ((row & 7) << 4))) = f2bf(hv);
            }
        }
    }
    __syncthreads();

    // GEMM2: wave covers cols wave*16 .. wave*16+15, K=256
    f4 acc2[2];
    acc2[0] = (f4){0.f, 0.f, 0.f, 0.f};
    acc2[1] = (f4){0.f, 0.f, 0.f, 0.f};
#pragma unroll
    for (int kk = 0; kk < 8; kk++) {
        bf8 a0 = *(const bf8*)(sH + ((lr * 512 + kk * 64 + lg * 16) ^ ((lr & 7) << 4)));
        bf8 a1 = *(const bf8*)(sH + (((16 + lr) * 512 + kk * 64 + lg * 16) ^ (((16 + lr) & 7) << 4)));
        bf8 b = *(const bf8*)(W2t + (size_t)(wave * 16 + lr) * HID + kk * 32 + lg * 8);
        acc2[0] = __builtin_amdgcn_mfma_f32_16x16x32_bf16(a0, b, acc2[0], 0, 0, 0);
        acc2[1] = __builtin_amdgcn_mfma_f32_16x16x32_bf16(a1, b, acc2[1], 0, 0, 0);
    }
    // write m (fp32) in place over this block's agg rows
    float* mf = (float*)agg;
    int colc = wave * 16 + lr;
#pragma unroll
    for (int h = 0; h < 2; h++)
#pragma unroll
        for (int ri = 0; ri < 4; ri++) {
            int row = h * 16 + lg * 4 + ri;
            mf[(row0 + row) * D_OUT + colc] = acc2[h][ri];
        }
}

// ---------------- layer-2 pull: out = A_norm @ m + b2 (fp32) ----------------

__global__ __launch_bounds__(256) void k_pull2(const int* __restrict__ row_ptr,
                                               const int* __restrict__ col,
                                               const float* __restrict__ wgt,
                                               const float* __restrict__ m,
                                               const float* __restrict__ dinv,
                                               const float* __restrict__ b2,
                                               float* __restrict__ out) {
    int wid = (blockIdx.x * blockDim.x + threadIdx.x) >> 6;
    int lane = threadIdx.x & 63;
    if (wid >= N_NODES) return;
    int beg = row_ptr[wid], end = row_ptr[wid + 1];
    float di = dinv[wid];
    float acc = di * di * m[(size_t)wid * D_OUT + lane] + b2[lane];
    int e = beg;
    for (; e + 4 <= end; e += 4) {
        int s0 = col[e], s1 = col[e + 1], s2 = col[e + 2], s3 = col[e + 3];
        float w_0 = wgt[e], w_1 = wgt[e + 1], w_2 = wgt[e + 2], w_3 = wgt[e + 3];
        float v0 = m[(size_t)s0 * D_OUT + lane];
        float v1 = m[(size_t)s1 * D_OUT + lane];
        float v2 = m[(size_t)s2 * D_OUT + lane];
        float v3 = m[(size_t)s3 * D_OUT + lane];
        acc += w_0 * v0;
        acc += w_1 * v1;
        acc += w_2 * v2;
        acc += w_3 * v3;
    }
    for (; e < end; e++) {
        acc += wgt[e] * m[(size_t)col[e] * D_OUT + lane];
    }
    out[(size_t)wid * D_OUT + lane] = acc;
}

// ---------------- launch ----------------

extern "C" void kernel_launch(void* const* d_in, const int* in_sizes, int n_in,
                              void* d_out, int out_size, void* d_ws, size_t ws_size,
                              hipStream_t stream) {
    const float* x  = (const float*)d_in[0];
    const int*   ei = (const int*)d_in[1];
    const float* W1 = (const float*)d_in[2];
    const float* b1 = (const float*)d_in[3];
    const float* W2 = (const float*)d_in[4];
    const float* b2 = (const float*)d_in[5];
    float* out = (float*)d_out;

    const int E = in_sizes[1] / 2;
    const int* src = ei;
    const int* dst = ei + E;

    // workspace layout — total 58,901,248 B (< 59.2 MB proven-good footprint)
    char* ws = (char*)d_ws;
    int* cnt            = (int*)(ws + 0);          // 100544 ints: cnt[0..100000) + bsum tail
    int* bsum           = cnt + 100096;            // 391 ints (within cnt alloc)
    int* row_ptr        = (int*)(ws + 402176);     // 100096 ints
    int* col            = (int*)(ws + 802560);     // 800000 ints
    float* dinv         = (float*)(ws + 4002560);  // 100096 f
    float* wgt          = (float*)(ws + 4402944);  // 800000 f
    unsigned short* W1t = (unsigned short*)(ws + 7602944);   // 256*128 bf16
    unsigned short* W2t = (unsigned short*)(ws + 7668480);   // 64*256 bf16
    unsigned short* xb  = (unsigned short*)(ws + 7701248);   // N*128 bf16 (25.6 MB)
    unsigned short* aggb = (unsigned short*)(ws + 33301248); // N*128 bf16 (25.6 MB), m in place

    const int NB = (N_NODES + 255) / 256;  // 391

    // conversions (independent of CSR)
    k_cvt_x<<<(N_NODES * D_IN / 4 + 255) / 256, 256, 0, stream>>>(x, xb, N_NODES * D_IN / 4);
    k_cvt_w1<<<(HID * D_IN + 255) / 256, 256, 0, stream>>>(W1, W1t);
    k_cvt_w2<<<(D_OUT * HID + 255) / 256, 256, 0, stream>>>(W2, W2t);

    // CSR build + normalization
    k_zero<<<NB, 256, 0, stream>>>(cnt, N_NODES);
    k_count<<<(E + 255) / 256, 256, 0, stream>>>(dst, E, cnt);
    k_dinv<<<NB, 256, 0, stream>>>(cnt, dinv, N_NODES);
    k_scan_part<<<NB, 256, 0, stream>>>(cnt, row_ptr, bsum, N_NODES);
    k_scan_base<<<1, 512, 0, stream>>>(bsum, row_ptr, NB, N_NODES);
    k_scan_fin<<<NB, 256, 0, stream>>>(row_ptr, bsum, cnt, N_NODES);  // cursor -> cnt
    k_fill<<<(E + 255) / 256, 256, 0, stream>>>(src, dst, E, dinv, cnt, col, wgt);

    // layer-1 pull (bf16 gather, 128 dims)
    k_pull1<<<(N_NODES * 64 + 255) / 256, 256, 0, stream>>>(row_ptr, col, wgt,
                                                            (const unsigned int*)xb, dinv,
                                                            (unsigned int*)aggb);

    // fused MFMA GEMM chain -> m (fp32, in place over aggb)
    k_fused_mfma<<<N_NODES / TR, 256, 0, stream>>>(aggb, W1t, b1, W2t);

    // layer-2 pull (64 dims) + bias
    k_pull2<<<(N_NODES * 64 + 255) / 256, 256, 0, stream>>>(row_ptr, col, wgt,
                                                            (const float*)aggb, dinv, b2, out);
}

// Round 5
// 230.033 us; speedup vs baseline: 10.0803x; 1.0558x over previous
//
#include <hip/hip_runtime.h>
#include <hip/hip_bf16.h>

#define N_NODES 100000
#define D_IN 128
#define HID 256
#define D_OUT 64
#define TR 32

typedef __attribute__((ext_vector_type(8))) short bf8;
typedef __attribute__((ext_vector_type(4))) float f4;

static __device__ __forceinline__ unsigned short f2bf(float f) {
    __hip_bfloat16 h = __float2bfloat16(f);
    return *reinterpret_cast<unsigned short*>(&h);
}
static __device__ __forceinline__ float bflo(unsigned int u) { return __uint_as_float(u << 16); }
static __device__ __forceinline__ float bfhi(unsigned int u) { return __uint_as_float(u & 0xffff0000u); }
static __device__ __forceinline__ float bfs(unsigned short u) {
    return __uint_as_float((unsigned int)u << 16);
}

// ---------------- fused prep: cvt_x | cvt_w1 | cvt_w2 | zero(cnt) ----------------
// block ranges: [0,12500) cvt_x, [12500,12628) W1t, [12628,12692) W2t, [12692,13083) zero

__global__ __launch_bounds__(256) void k_prep(const float* __restrict__ x,
                                              unsigned long long* __restrict__ xb,
                                              const float* __restrict__ W1,
                                              unsigned short* __restrict__ W1t,
                                              const float* __restrict__ W2,
                                              unsigned short* __restrict__ W2t,
                                              int* __restrict__ cnt) {
    int b = blockIdx.x, t = threadIdx.x;
    if (b < 12500) {
        int i = b * 256 + t;  // float4 index over x
        float4 v = ((const float4*)x)[i];
        unsigned long long o = (unsigned long long)f2bf(v.x) |
                               ((unsigned long long)f2bf(v.y) << 16) |
                               ((unsigned long long)f2bf(v.z) << 32) |
                               ((unsigned long long)f2bf(v.w) << 48);
        xb[i] = o;
    } else if (b < 12628) {
        int i = (b - 12500) * 256 + t;  // 32768 elems
        int n = i >> 7, k = i & 127;
        W1t[i] = f2bf(W1[k * HID + n]);
    } else if (b < 12692) {
        int i = (b - 12628) * 256 + t;  // 16384 elems
        int n = i >> 8, k = i & 255;
        W2t[i] = f2bf(W2[k * D_OUT + n]);
    } else {
        int i = (b - 12692) * 256 + t;
        if (i < N_NODES) cnt[i] = 0;
    }
}

// ---------------- CSR build ----------------

__global__ void k_count(const int* __restrict__ dst, int E, int* __restrict__ cnt) {
    int e = blockIdx.x * blockDim.x + threadIdx.x;
    if (e < E) atomicAdd(&cnt[dst[e]], 1);
}

// per-block exclusive prefix into row_ptr, block totals into bsum; dinv fused
__global__ __launch_bounds__(256) void k_scan_part(const int* __restrict__ cnt,
                                                   int* __restrict__ row_ptr,
                                                   int* __restrict__ bsum,
                                                   float* __restrict__ dinv, int n) {
    __shared__ int s[256];
    int t = threadIdx.x, i = blockIdx.x * 256 + t;
    int v = (i < n) ? cnt[i] : 0;
    s[t] = v;
    __syncthreads();
    for (int off = 1; off < 256; off <<= 1) {
        int u = (t >= off) ? s[t - off] : 0;
        __syncthreads();
        s[t] += u;
        __syncthreads();
    }
    if (i < n) {
        row_ptr[i] = s[t] - v;  // exclusive within block
        dinv[i] = rsqrtf((float)v + 1.0f);  // +1 self-loop
    }
    if (t == 255) bsum[blockIdx.x] = s[255];
}

// single block: exclusive-scan bsum in place; write row_ptr[n] = grand total
__global__ __launch_bounds__(512) void k_scan_base(int* __restrict__ bsum,
                                                   int* __restrict__ row_ptr, int nb, int n) {
    __shared__ int s[512];
    int t = threadIdx.x;
    int v = (t < nb) ? bsum[t] : 0;
    s[t] = v;
    __syncthreads();
    for (int off = 1; off < 512; off <<= 1) {
        int u = (t >= off) ? s[t - off] : 0;
        __syncthreads();
        s[t] += u;
        __syncthreads();
    }
    if (t < nb) bsum[t] = s[t] - v;  // exclusive base
    if (t == 511) row_ptr[n] = s[511];
}

// add block bases; final row_ptr and cursor (cursor aliases cnt — counts are dead)
__global__ void k_scan_fin(int* __restrict__ row_ptr, const int* __restrict__ bsum,
                           int* __restrict__ cursor, int n) {
    int i = blockIdx.x * blockDim.x + threadIdx.x;
    if (i >= n) return;
    int v = row_ptr[i] + bsum[i >> 8];
    row_ptr[i] = v;
    cursor[i] = v;
}

// one combined int2 {src, wgt} store per edge — halves dirtied-line write-back
__global__ void k_fill(const int* __restrict__ src, const int* __restrict__ dst, int E,
                       const float* __restrict__ dinv, int* __restrict__ cursor,
                       int2* __restrict__ cw) {
    int e = blockIdx.x * blockDim.x + threadIdx.x;
    if (e >= E) return;
    int s = src[e], d = dst[e];
    int pos = atomicAdd(&cursor[d], 1);
    int2 v;
    v.x = s;
    v.y = __float_as_int(dinv[s] * dinv[d]);
    cw[pos] = v;
}

// ---------------- layer-1 pull: agg = A_norm @ x, bf16 in / bf16 out ----------------
// one wave per node; lane holds cols {2*lane, 2*lane+1} packed bf16x2

__global__ __launch_bounds__(256) void k_pull1(const int* __restrict__ row_ptr,
                                               const int2* __restrict__ cw,
                                               const unsigned int* __restrict__ xb,
                                               const float* __restrict__ dinv,
                                               unsigned int* __restrict__ agg) {
    int wid = (blockIdx.x * blockDim.x + threadIdx.x) >> 6;
    int lane = threadIdx.x & 63;
    if (wid >= N_NODES) return;
    int beg = row_ptr[wid], end = row_ptr[wid + 1];
    float di = dinv[wid];
    float w0 = di * di;
    unsigned int u = xb[(size_t)wid * 64 + lane];
    float ax = w0 * bflo(u), ay = w0 * bfhi(u);
    int e = beg;
    for (; e + 4 <= end; e += 4) {
        int2 c0 = cw[e], c1 = cw[e + 1], c2 = cw[e + 2], c3 = cw[e + 3];
        unsigned int u0 = xb[(size_t)c0.x * 64 + lane];
        unsigned int u1 = xb[(size_t)c1.x * 64 + lane];
        unsigned int u2 = xb[(size_t)c2.x * 64 + lane];
        unsigned int u3 = xb[(size_t)c3.x * 64 + lane];
        float w_0 = __int_as_float(c0.y), w_1 = __int_as_float(c1.y);
        float w_2 = __int_as_float(c2.y), w_3 = __int_as_float(c3.y);
        ax += w_0 * bflo(u0);
        ay += w_0 * bfhi(u0);
        ax += w_1 * bflo(u1);
        ay += w_1 * bfhi(u1);
        ax += w_2 * bflo(u2);
        ay += w_2 * bfhi(u2);
        ax += w_3 * bflo(u3);
        ay += w_3 * bfhi(u3);
    }
    for (; e < end; e++) {
        int2 c = cw[e];
        float w = __int_as_float(c.y);
        unsigned int uu = xb[(size_t)c.x * 64 + lane];
        ax += w * bflo(uu);
        ay += w * bfhi(uu);
    }
    unsigned int o = (unsigned int)f2bf(ax) | ((unsigned int)f2bf(ay) << 16);
    agg[(size_t)wid * 64 + lane] = o;
}

// ---------------- fused GEMM chain (MFMA): m = relu(agg@W1+b1)@W2, bf16 out ----------------
// m (64 bf16 = 128 B/row) written IN PLACE into the first half of each agg row
// (agg row = 256 B, stride kept at 128 ushorts). Block b writes only rows it
// staged to LDS before the first barrier -> no cross-block hazard.

__global__ __launch_bounds__(256) void k_fused_mfma(unsigned short* __restrict__ agg,
                                                    const unsigned short* __restrict__ W1t,
                                                    const float* __restrict__ b1,
                                                    const unsigned short* __restrict__ W2t) {
    __shared__ char sA[TR * D_IN * 2];  // 8 KB, row stride 256B
    __shared__ char sH[TR * HID * 2];   // 16 KB, row stride 512B
    int t = threadIdx.x, wave = t >> 6, lane = t & 63;
    int lr = lane & 15, lg = lane >> 4;
    size_t row0 = (size_t)blockIdx.x * TR;

    // stage A tile: 512 x 16B chunks, XOR swizzle byte ^= (row&7)<<4
    {
        const float4* g = (const float4*)(agg + row0 * D_IN);
#pragma unroll
        for (int c0 = 0; c0 < 2; c0++) {
            int c = c0 * 256 + t;
            int row = c >> 4;
            *(float4*)(sA + ((c * 16) ^ ((row & 7) << 4))) = g[c];
        }
    }
    __syncthreads();

    // GEMM1: wave covers cols wave*64 .. wave*64+63 (4 tiles), both 16-row halves
    f4 acc1[4][2];
#pragma unroll
    for (int tt = 0; tt < 4; tt++)
#pragma unroll
        for (int h = 0; h < 2; h++) acc1[tt][h] = (f4){0.f, 0.f, 0.f, 0.f};

#pragma unroll
    for (int kk = 0; kk < 4; kk++) {
        bf8 a0 = *(const bf8*)(sA + ((lr * 256 + kk * 64 + lg * 16) ^ ((lr & 7) << 4)));
        bf8 a1 = *(const bf8*)(sA + (((16 + lr) * 256 + kk * 64 + lg * 16) ^ (((16 + lr) & 7) << 4)));
#pragma unroll
        for (int tt = 0; tt < 4; tt++) {
            bf8 b = *(const bf8*)(W1t + (size_t)(wave * 64 + tt * 16 + lr) * D_IN + kk * 32 + lg * 8);
            acc1[tt][0] = __builtin_amdgcn_mfma_f32_16x16x32_bf16(a0, b, acc1[tt][0], 0, 0, 0);
            acc1[tt][1] = __builtin_amdgcn_mfma_f32_16x16x32_bf16(a1, b, acc1[tt][1], 0, 0, 0);
        }
    }

    // epilogue 1: bias + relu + cvt bf16 -> sH
#pragma unroll
    for (int tt = 0; tt < 4; tt++) {
        int colc = wave * 64 + tt * 16 + lr;
        float bias = b1[colc];
#pragma unroll
        for (int h = 0; h < 2; h++) {
#pragma unroll
            for (int ri = 0; ri < 4; ri++) {
                int row = h * 16 + lg * 4 + ri;
                float hv = acc1[tt][h][ri] + bias;
                hv = hv > 0.f ? hv : 0.f;
                *(unsigned short*)(sH + ((row * 512 + colc * 2) ^ ((row & 7) << 4))) = f2bf(hv);
            }
        }
    }
    __syncthreads();

    // GEMM2: wave covers cols wave*16 .. wave*16+15, K=256
    f4 acc2[2];
    acc2[0] = (f4){0.f, 0.f, 0.f, 0.f};
    acc2[1] = (f4){0.f, 0.f, 0.f, 0.f};
#pragma unroll
    for (int kk = 0; kk < 8; kk++) {
        bf8 a0 = *(const bf8*)(sH + ((lr * 512 + kk * 64 + lg * 16) ^ ((lr & 7) << 4)));
        bf8 a1 = *(const bf8*)(sH + (((16 + lr) * 512 + kk * 64 + lg * 16) ^ (((16 + lr) & 7) << 4)));
        bf8 b = *(const bf8*)(W2t + (size_t)(wave * 16 + lr) * HID + kk * 32 + lg * 8);
        acc2[0] = __builtin_amdgcn_mfma_f32_16x16x32_bf16(a0, b, acc2[0], 0, 0, 0);
        acc2[1] = __builtin_amdgcn_mfma_f32_16x16x32_bf16(a1, b, acc2[1], 0, 0, 0);
    }
    // write m (bf16) into first 64 ushorts of each owned agg row (stride 128)
    int colc = wave * 16 + lr;
#pragma unroll
    for (int h = 0; h < 2; h++)
#pragma unroll
        for (int ri = 0; ri < 4; ri++) {
            int row = h * 16 + lg * 4 + ri;
            agg[(row0 + row) * 128 + colc] = f2bf(acc2[h][ri]);
        }
}

// ---------------- layer-2 pull: out = A_norm @ m + b2 (bf16 gather, fp32 out) ----------------
// m rows: 64 bf16 at stride 128 ushorts inside the agg buffer

__global__ __launch_bounds__(256) void k_pull2(const int* __restrict__ row_ptr,
                                               const int2* __restrict__ cw,
                                               const unsigned short* __restrict__ m,
                                               const float* __restrict__ dinv,
                                               const float* __restrict__ b2,
                                               float* __restrict__ out) {
    int wid = (blockIdx.x * blockDim.x + threadIdx.x) >> 6;
    int lane = threadIdx.x & 63;
    if (wid >= N_NODES) return;
    int beg = row_ptr[wid], end = row_ptr[wid + 1];
    float di = dinv[wid];
    float acc = di * di * bfs(m[(size_t)wid * 128 + lane]) + b2[lane];
    int e = beg;
    for (; e + 4 <= end; e += 4) {
        int2 c0 = cw[e], c1 = cw[e + 1], c2 = cw[e + 2], c3 = cw[e + 3];
        float v0 = bfs(m[(size_t)c0.x * 128 + lane]);
        float v1 = bfs(m[(size_t)c1.x * 128 + lane]);
        float v2 = bfs(m[(size_t)c2.x * 128 + lane]);
        float v3 = bfs(m[(size_t)c3.x * 128 + lane]);
        acc += __int_as_float(c0.y) * v0;
        acc += __int_as_float(c1.y) * v1;
        acc += __int_as_float(c2.y) * v2;
        acc += __int_as_float(c3.y) * v3;
    }
    for (; e < end; e++) {
        int2 c = cw[e];
        acc += __int_as_float(c.y) * bfs(m[(size_t)c.x * 128 + lane]);
    }
    out[(size_t)wid * D_OUT + lane] = acc;
}

// ---------------- launch ----------------

extern "C" void kernel_launch(void* const* d_in, const int* in_sizes, int n_in,
                              void* d_out, int out_size, void* d_ws, size_t ws_size,
                              hipStream_t stream) {
    const float* x  = (const float*)d_in[0];
    const int*   ei = (const int*)d_in[1];
    const float* W1 = (const float*)d_in[2];
    const float* b1 = (const float*)d_in[3];
    const float* W2 = (const float*)d_in[4];
    const float* b2 = (const float*)d_in[5];
    float* out = (float*)d_out;

    const int E = in_sizes[1] / 2;
    const int* src = ei;
    const int* dst = ei + E;

    // workspace layout — total 58,901,248 B (same proven-good footprint as R3)
    char* ws = (char*)d_ws;
    int* cnt            = (int*)(ws + 0);          // 100096 ints (+bsum tail)
    int* bsum           = cnt + 100096;            // 391 ints
    int* row_ptr        = (int*)(ws + 402176);     // 100096 ints
    int2* cw            = (int2*)(ws + 802560);    // 800000 int2 (6.4 MB)
    float* dinv         = (float*)(ws + 7202560);  // 100096 f
    unsigned short* W1t = (unsigned short*)(ws + 7602944);   // 256*128 bf16
    unsigned short* W2t = (unsigned short*)(ws + 7668480);   // 64*256 bf16
    unsigned short* xb  = (unsigned short*)(ws + 7701248);   // N*128 bf16 (25.6 MB)
    unsigned short* aggb = (unsigned short*)(ws + 33301248); // N*128 bf16 (25.6 MB), m in place

    const int NB = (N_NODES + 255) / 256;  // 391

    // fused prep: cvt_x | cvt_w1 | cvt_w2 | zero(cnt)
    k_prep<<<13083, 256, 0, stream>>>(x, (unsigned long long*)xb, W1, W1t, W2, W2t, cnt);

    // CSR build (dinv fused into scan_part)
    k_count<<<(E + 255) / 256, 256, 0, stream>>>(dst, E, cnt);
    k_scan_part<<<NB, 256, 0, stream>>>(cnt, row_ptr, bsum, dinv, N_NODES);
    k_scan_base<<<1, 512, 0, stream>>>(bsum, row_ptr, NB, N_NODES);
    k_scan_fin<<<NB, 256, 0, stream>>>(row_ptr, bsum, cnt, N_NODES);  // cursor -> cnt
    k_fill<<<(E + 255) / 256, 256, 0, stream>>>(src, dst, E, dinv, cnt, cw);

    // layer-1 pull (bf16 gather, 128 dims)
    k_pull1<<<(N_NODES * 64 + 255) / 256, 256, 0, stream>>>(row_ptr, cw,
                                                            (const unsigned int*)xb, dinv,
                                                            (unsigned int*)aggb);

    // fused MFMA GEMM chain -> m (bf16, in place over aggb)
    k_fused_mfma<<<N_NODES / TR, 256, 0, stream>>>(aggb, W1t, b1, W2t);

    // layer-2 pull (64 dims, bf16 gather) + bias
    k_pull2<<<(N_NODES * 64 + 255) / 256, 256, 0, stream>>>(row_ptr, cw, aggb, dinv, b2, out);
}